// Round 10
// baseline (106.556 us; speedup 1.0000x reference)
//
#include <hip/hip_runtime.h>
#include <math.h>

typedef unsigned short ushort_t;
typedef unsigned int uint32_tt;
typedef __attribute__((ext_vector_type(8))) short bf16x8;
typedef __attribute__((ext_vector_type(4))) float f32x4;

#define NR   8
#define NK   10
#define ND   256
#define NDL  10
#define NB   4096
#define NN   100
#define NP   112      // phase-1 padded n (7*16)
#define NP2  128      // phase-3 padded K over n (4*32)

// ---- workspace layout (bytes) ----
#define WS_GP   0                          // fp32 Gp[8][1000]
#define WS_XB   32768                      // bf16 x[4096][256] = 2,097,152
#define WS_U1   (32768 + 2097152)          // bf16 U1[8][112][256] (n-major, D contig)
#define WS_U2   (WS_U1 + 458752)           // bf16 U2[8][256][128] (D-major, n contig)
#define WS_NEED (WS_U2 + 524288)           // 3,112,960

__device__ __forceinline__ ushort_t f2bf(float f) {
    uint32_tt u = __float_as_uint(f);
    u = (u + 0x7FFF + ((u >> 16) & 1)) >> 16;   // RNE
    return (ushort_t)u;
}

// =====================================================================
// Prep: bid<1024: x->bf16 (coalesced). bid>=1024: one block per (r,k):
// load Us[rk] 10KB coalesced -> LDS, emit Gram + U1 slice + U2 slice.
// =====================================================================
__global__ __launch_bounds__(256) void prep_kernel(const float* __restrict__ x,
                                                   const float* __restrict__ Us,
                                                   char* __restrict__ ws) {
    __shared__ float lu[ND * NDL];     // 10 KB, layout [D][d] stride 10
    const int bid = blockIdx.x, tid = threadIdx.x;

    if (bid < 1024) {
        ushort_t* xb = (ushort_t*)(ws + WS_XB);
        int i = bid * 256 + tid;
        float4 v = ((const float4*)x)[i];
        uint32_tt p0 = (uint32_tt)f2bf(v.x) | ((uint32_tt)f2bf(v.y) << 16);
        uint32_tt p1 = (uint32_tt)f2bf(v.z) | ((uint32_tt)f2bf(v.w) << 16);
        ((uint2*)xb)[i] = make_uint2(p0, p1);
        return;
    }

    const int rk = bid - 1024;               // 0..79
    const int r  = rk / NK, k = rk - r * NK;
    const float* U = Us + (size_t)rk * ND * NDL;
    for (int i = tid; i < 640; i += 256)
        ((float4*)lu)[i] = ((const float4*)U)[i];
    __syncthreads();

    // ---- Gram: Gp = 10*I - 5*U^T U (fp32 -> logits stay accurate) ----
    float* Gp = (float*)(ws + WS_GP);
    if (tid < NDL * NDL) {
        int d1 = tid / NDL, d2 = tid - d1 * NDL;
        float acc = 0.f;
        #pragma unroll 8
        for (int Di = 0; Di < ND; ++Di)
            acc += lu[Di * NDL + d1] * lu[Di * NDL + d2];
        Gp[(size_t)rk * 100 + tid] = (d1 == d2 ? 10.0f : 0.0f) - 5.0f * acc;
    }

    // ---- U1[r][k*10+d][D] bf16, coalesced in D ----
    ushort_t* u1 = (ushort_t*)(ws + WS_U1);
    for (int p = tid; p < ND * NDL; p += 256) {
        int d = p >> 8, D = p & 255;
        u1[((size_t)r * NP + k * NDL + d) * ND + D] = f2bf(lu[D * NDL + d]);
    }

    // ---- U2[r][D][k*10..k*10+10) bf16, one D-row per thread ----
    ushort_t* u2 = (ushort_t*)(ws + WS_U2);
    {
        int D = tid;
        uint32_tt* dst = (uint32_tt*)(u2 + ((size_t)r * ND + D) * NP2 + k * NDL);
        const float* src = lu + D * NDL;
        #pragma unroll
        for (int j = 0; j < 5; ++j)
            dst[j] = (uint32_tt)f2bf(src[2 * j]) | ((uint32_tt)f2bf(src[2 * j + 1]) << 16);
    }

    // ---- zero pads (k==9 block only) ----
    if (k == NK - 1) {
        for (int p = tid; p < 12 * ND; p += 256) {
            int n = p >> 8, D = p & 255;
            u1[((size_t)r * NP + 100 + n) * ND + D] = 0;
        }
        uint32_tt* u2u = (uint32_tt*)u2;
        #pragma unroll
        for (int j = 0; j < 14; ++j)
            u2u[((size_t)r * ND + tid) * (NP2 / 2) + 50 + j] = 0;
    }
}

// =====================================================================
// Main MFMA kernel, grid 256 x 256 threads, 1 block/CU, 4 items/block.
// r = bid&7 = XCD slot: each r's U1/U2 is HBM-read once per XCD.
// REGISTER-RESIDENT U: all U1 (32 frags) + U2 (32 frags) A-operands are
// loaded ONCE into VGPRs and reused across 4 b-tile items — per-item
// global traffic is just the 8 x-fragments, prefetched one item ahead.
// lb(256,1): no VGPR cap (1 wave/SIMD intentional; latency hidden by
// register residency, not TLP).
// R9 BUG FIX: wTb pad rows 16..31 were left unzeroed -> garbage bf16
// (incl. NaN patterns) x 0 = NaN. Both pad statements restored.
// =====================================================================
__global__ __launch_bounds__(256, 1) void ksub_mfma7(const char* __restrict__ ws,
                                                     float* __restrict__ out) {
    __shared__ __align__(16) char smem[37280];
    float*    zbuf = (float*)smem;               // [32][100] fp32
    ushort_t* wTb  = (ushort_t*)smem;            // [32][136] bf16 (overlay)
    float*    ot   = (float*)smem;               // [32][260] fp32 (overlay, epilogue)
    float*    gp   = (float*)(smem + 33280);     // [1000] fp32

    const int tid  = threadIdx.x;
    const int w    = tid >> 6;
    const int lane = tid & 63;
    const int c    = lane & 15;
    const int q    = lane >> 4;
    const int bid  = blockIdx.x;
    const int r    = bid & 7;                    // r == XCD slot
    const int jgrp = bid >> 3;                   // 0..31
    const int bloc = (w & 1) * 16 + c;           // local b col 0..31
    const int pair = w >> 1;                     // wave pair 0/1
    const int Dbase = pair * 128;

    const ushort_t* xbase = (const ushort_t*)(ws + WS_XB);
    const ushort_t* u1g = (const ushort_t*)(ws + WS_U1) + (size_t)r * NP * ND + c * ND + q * 8;
    const ushort_t* u2g = (const ushort_t*)(ws + WS_U2) + (size_t)r * ND * NP2 + c * NP2 + q * 8;
    const float*    gpg = (const float*)(ws + WS_GP) + (size_t)r * 1000;

    for (int i = tid; i < 1000; i += 256) gp[i] = gpg[i];

    // ---------------- prologue: U1 + U2 fragments -> registers ----------------
    bf16x8 u1f[32];                // [Dc*4+tt]; t = pair*4+tt (t<7 valid)
    #pragma unroll
    for (int Dc = 0; Dc < 8; ++Dc) {
        #pragma unroll
        for (int tt = 0; tt < 4; ++tt) {
            int t = pair * 4 + tt;
            if (t < 7)
                u1f[Dc * 4 + tt] = *(const bf16x8*)(u1g + t * 16 * ND + Dc * 32);
        }
    }
    bf16x8 u2f[32];                // [nc*8+jj]; rows Dbase + jj*16 + c
    #pragma unroll
    for (int nc = 0; nc < 4; ++nc) {
        #pragma unroll
        for (int jj = 0; jj < 8; ++jj)
            u2f[nc * 8 + jj] = *(const bf16x8*)(u2g + (size_t)(Dbase + jj * 16) * NP2 + nc * 32);
    }

    // x fragments for item 0
    bf16x8 xfr[8], xfrn[8];
    {
        const ushort_t* xb = xbase + (size_t)((jgrp * 4 + 0) * 32 + bloc) * ND + q * 8;
        #pragma unroll
        for (int Dc = 0; Dc < 8; ++Dc)
            xfr[Dc] = *(const bf16x8*)(xb + Dc * 32);
    }

    for (int it = 0; it < 4; ++it) {
        const int b0 = (jgrp * 4 + it) * 32;

        // ---- prefetch next item's x fragments (overlaps phase-1 MFMA) ----
        if (it < 3) {
            const ushort_t* xb = xbase + (size_t)(b0 + 32 + bloc) * ND + q * 8;
            #pragma unroll
            for (int Dc = 0; Dc < 8; ++Dc)
                xfrn[Dc] = *(const bf16x8*)(xb + Dc * 32);
        }

        // ---------------- phase 1: all-register MFMA ----------------
        f32x4 acc1[4];
        #pragma unroll
        for (int t = 0; t < 4; ++t) acc1[t] = (f32x4){0.f, 0.f, 0.f, 0.f};
        #pragma unroll
        for (int Dc = 0; Dc < 8; ++Dc) {
            #pragma unroll
            for (int tt = 0; tt < 4; ++tt) {
                int t = pair * 4 + tt;
                if (t < 7)
                    acc1[tt] = __builtin_amdgcn_mfma_f32_16x16x32_bf16(u1f[Dc * 4 + tt], xfr[Dc], acc1[tt], 0, 0, 0);
            }
        }

        // ---- dump Z^T C-frags: row n = t*16+q*4+reg, col b = bloc ----
        #pragma unroll
        for (int tt = 0; tt < 4; ++tt) {
            int t = pair * 4 + tt;
            if (t < 7) {
                #pragma unroll
                for (int rg = 0; rg < 4; ++rg) {
                    int n = t * 16 + q * 4 + rg;
                    if (n < NN) zbuf[bloc * 100 + n] = acc1[tt][rg];
                }
            }
        }
        __syncthreads();

        // ---------------- softmax: b = tid>>3, k split on 8 lanes ----------------
        const int bsm = tid >> 3;
        const int kq  = tid & 7;
        float zk[2][10], ee[2];
        {
            const float* zr = zbuf + bsm * 100;
            float L[2];
            #pragma unroll
            for (int jj = 0; jj < 2; ++jj) {
                int k = kq + 8 * jj;
                L[jj] = -1e30f;
                if (k < NK) {
                    #pragma unroll
                    for (int d = 0; d < 10; ++d) zk[jj][d] = zr[k * 10 + d];
                    const float* g = gp + k * 100;
                    float acc = 0.f;
                    #pragma unroll
                    for (int d1 = 0; d1 < 10; ++d1) {
                        float t2 = 0.f;
                        #pragma unroll
                        for (int d2 = 0; d2 < 10; ++d2) t2 += g[d1 * 10 + d2] * zk[jj][d2];
                        acc += t2 * zk[jj][d1];
                    }
                    L[jj] = acc;
                }
            }
            float m = fmaxf(L[0], L[1]);
            m = fmaxf(m, __shfl_xor(m, 1));
            m = fmaxf(m, __shfl_xor(m, 2));
            m = fmaxf(m, __shfl_xor(m, 4));
            float s = 0.f;
            #pragma unroll
            for (int jj = 0; jj < 2; ++jj) {
                ee[jj] = (kq + 8 * jj < NK) ? __expf(L[jj] - m) : 0.f;
                s += ee[jj];
            }
            s += __shfl_xor(s, 1);
            s += __shfl_xor(s, 2);
            s += __shfl_xor(s, 4);
            float inv = 1.0f / s;
            #pragma unroll
            for (int jj = 0; jj < 2; ++jj) ee[jj] *= inv;
        }
        __syncthreads();               // all zbuf reads done; wTb overlay safe

        #pragma unroll
        for (int jj = 0; jj < 2; ++jj) {
            int k = kq + 8 * jj;
            if (k < NK) {
                #pragma unroll
                for (int d = 0; d < 10; ++d)
                    wTb[bsm * 136 + k * 10 + d] = f2bf(ee[jj] * zk[jj][d]);
            }
        }
        // zero-pad wTb n in [100,128): 14 uints per row, ALL 32 rows
        {
            int row = tid >> 4, p = tid & 15;
            if (p < 14) ((uint32_tt*)wTb)[row * 68 + 50 + p] = 0;
            row += 16;
            if (p < 14) ((uint32_tt*)wTb)[row * 68 + 50 + p] = 0;
        }
        __syncthreads();

        // ---------------- phase 3: all-register A, LDS B ----------------
        f32x4 acc3[8];
        #pragma unroll
        for (int t = 0; t < 8; ++t) acc3[t] = (f32x4){0.f, 0.f, 0.f, 0.f};
        #pragma unroll
        for (int nc = 0; nc < 4; ++nc) {
            bf16x8 bfr = *(const bf16x8*)(wTb + bloc * 136 + nc * 32 + q * 8);
            #pragma unroll
            for (int jj = 0; jj < 8; ++jj)
                acc3[jj] = __builtin_amdgcn_mfma_f32_16x16x32_bf16(u2f[nc * 8 + jj], bfr, acc3[jj], 0, 0, 0);
        }

        // ---- epilogue: LDS transpose -> per-row 1KB plain stores ----
        __syncthreads();               // wTb reads complete before ot overlay
        #pragma unroll
        for (int jj = 0; jj < 8; ++jj)
            *(f32x4*)(ot + bloc * 260 + Dbase + jj * 16 + q * 4) = acc3[jj];
        __syncthreads();
        const size_t orow = (size_t)r * NB + b0;
        #pragma unroll
        for (int i = 0; i < 8; ++i) {
            int g4 = i * 256 + tid;        // float4 index over 32 rows x 64
            int b  = g4 >> 6;
            int c4 = g4 & 63;
            f32x4 v = *(const f32x4*)(ot + b * 260 + c4 * 4);
            *(f32x4*)(out + (orow + b) * ND + c4 * 4) = v;
        }
        __syncthreads();               // ot reads done before next item's zbuf writes

        // rotate x double-buffer
        if (it < 3) {
            #pragma unroll
            for (int Dc = 0; Dc < 8; ++Dc) xfr[Dc] = xfrn[Dc];
        }
    }
}

// =====================================================================
// Fallback (round-2 verified path) if ws is too small for bf16 buffers
// =====================================================================
#define XS_S 68
#define US_S 132
#define ZB_S 104
#define WT_S 68
#define U2_S 68
#define OFF_WT 0
#define OFF_SH 6800
#define OFF_GP 13600
#define SMEM_F 14600

__global__ __launch_bounds__(128) void gram_kernel(const float* __restrict__ Us,
                                                   float* __restrict__ Gp) {
    int rk = blockIdx.x;
    const float* U = Us + (size_t)rk * ND * NDL;
    __shared__ float u[ND * NDL];
    for (int i = threadIdx.x; i < ND * NDL; i += blockDim.x) u[i] = U[i];
    __syncthreads();
    int e = threadIdx.x;
    if (e < NDL * NDL) {
        int d1 = e / NDL, d2 = e % NDL;
        float acc = 0.f;
        #pragma unroll 8
        for (int Di = 0; Di < ND; ++Di)
            acc += u[Di * NDL + d1] * u[Di * NDL + d2];
        Gp[(size_t)rk * (NDL * NDL) + e] = (d1 == d2 ? 10.0f : 0.0f) - 5.0f * acc;
    }
}

__global__ __launch_bounds__(256, 2) void ksub_fused(const float* __restrict__ x,
                                                     const float* __restrict__ Us,
                                                     const float* __restrict__ Gp,
                                                     float* __restrict__ out) {
    __shared__ float smemf[SMEM_F];
    float* wT   = smemf + OFF_WT;
    float* xsf  = smemf + OFF_SH;
    float* usf  = smemf + OFF_SH + 2176;
    float* zbuf = smemf + OFF_SH;
    float* u2   = smemf + OFF_SH;
    float* gp   = smemf + OFF_GP;

    const int tid = threadIdx.x;
    const int r   = blockIdx.y;
    const int b0  = blockIdx.x * 64;

    for (int i = tid; i < NK * NDL * NDL; i += 256)
        gp[i] = Gp[(size_t)r * (NK * NDL * NDL) + i];

    const int nt = tid & 15;
    const int bt = tid >> 4;
    float acc[4][8];
    #pragma unroll
    for (int j = 0; j < 4; ++j)
        #pragma unroll
        for (int i = 0; i < 8; ++i) acc[j][i] = 0.f;

    for (int cch = 0; cch < 8; ++cch) {
        __syncthreads();
        for (int i = tid; i < 512; i += 256) {
            int b = i >> 3, f = i & 7;
            float4 v = ((const float4*)(x + (size_t)(b0 + b) * ND))[cch * 8 + f];
            float* dst = xsf + (f * 4) * XS_S + b;
            dst[0] = v.x; dst[XS_S] = v.y; dst[2 * XS_S] = v.z; dst[3 * XS_S] = v.w;
        }
        for (int p = tid; p < 320; p += 256) {
            int k = p >> 5, Dl = p & 31;
            const float* g = Us + ((size_t)((r * NK + k) * ND) + cch * 32 + Dl) * NDL;
            float* dst = usf + Dl * US_S + k * NDL;
            #pragma unroll
            for (int d = 0; d < 10; ++d) dst[d] = g[d];
        }
        __syncthreads();
        #pragma unroll 4
        for (int Dl = 0; Dl < 32; ++Dl) {
            float4 xv = *(const float4*)(xsf + Dl * XS_S + bt * 4);
            float4 ua = *(const float4*)(usf + Dl * US_S + nt * 8);
            float4 ub = *(const float4*)(usf + Dl * US_S + nt * 8 + 4);
            float xa[4] = {xv.x, xv.y, xv.z, xv.w};
            float uu[8] = {ua.x, ua.y, ua.z, ua.w, ub.x, ub.y, ub.z, ub.w};
            #pragma unroll
            for (int j = 0; j < 4; ++j)
                #pragma unroll
                for (int i = 0; i < 8; ++i) acc[j][i] += xa[j] * uu[i];
        }
    }
    __syncthreads();
    if (nt < 12) {
        #pragma unroll
        for (int j = 0; j < 4; ++j) {
            float* zp = zbuf + (bt * 4 + j) * ZB_S + nt * 8;
            *(float4*)(zp)     = make_float4(acc[j][0], acc[j][1], acc[j][2], acc[j][3]);
            *(float4*)(zp + 4) = make_float4(acc[j][4], acc[j][5], acc[j][6], acc[j][7]);
        }
    } else if (nt == 12) {
        #pragma unroll
        for (int j = 0; j < 4; ++j) {
            float* zp = zbuf + (bt * 4 + j) * ZB_S + 96;
            *(float4*)(zp) = make_float4(acc[j][0], acc[j][1], acc[j][2], acc[j][3]);
        }
    }
    __syncthreads();
    if (tid < 64) {
        const int b_l = tid;
        const float* zrow = zbuf + b_l * ZB_S;
        float L[10];
        #pragma unroll
        for (int k = 0; k < NK; ++k) {
            float zkk[10];
            #pragma unroll
            for (int d = 0; d < 10; ++d) zkk[d] = zrow[k * 10 + d];
            const float* g = gp + k * 100;
            float a2 = 0.f;
            #pragma unroll
            for (int d1 = 0; d1 < 10; ++d1) {
                float t = 0.f;
                #pragma unroll
                for (int d2 = 0; d2 < 10; ++d2) t += g[d1 * 10 + d2] * zkk[d2];
                a2 += t * zkk[d1];
            }
            L[k] = a2;
        }
        float m = L[0];
        #pragma unroll
        for (int k = 1; k < NK; ++k) m = fmaxf(m, L[k]);
        float e[10], s = 0.f;
        #pragma unroll
        for (int k = 0; k < NK; ++k) { e[k] = __expf(L[k] - m); s += e[k]; }
        float inv = 1.0f / s;
        #pragma unroll
        for (int k = 0; k < NK; ++k) {
            float ck = e[k] * inv;
            #pragma unroll
            for (int d = 0; d < 10; ++d)
                wT[(k * 10 + d) * WT_S + b_l] = ck * zrow[k * 10 + d];
        }
    }
    const int Dt  = tid & 15;
    const int bt2 = tid >> 4;
    for (int c2 = 0; c2 < 4; ++c2) {
        __syncthreads();
        for (int p = tid; p < 640; p += 256) {
            int k = p >> 6, Dl = p & 63;
            const float* g = Us + ((size_t)((r * NK + k) * ND) + c2 * 64 + Dl) * NDL;
            float* dst = u2 + (k * NDL) * U2_S + Dl;
            #pragma unroll
            for (int d = 0; d < 10; ++d) dst[d * U2_S] = g[d];
        }
        __syncthreads();
        float o[4][4];
        #pragma unroll
        for (int j = 0; j < 4; ++j)
            #pragma unroll
            for (int i = 0; i < 4; ++i) o[j][i] = 0.f;
        #pragma unroll 4
        for (int n = 0; n < NN; ++n) {
            float4 wv = *(const float4*)(wT + n * WT_S + bt2 * 4);
            float4 uv = *(const float4*)(u2 + n * U2_S + Dt * 4);
            float wa[4] = {wv.x, wv.y, wv.z, wv.w};
            float ub[4] = {uv.x, uv.y, uv.z, uv.w};
            #pragma unroll
            for (int j = 0; j < 4; ++j)
                #pragma unroll
                for (int i = 0; i < 4; ++i) o[j][i] += wa[j] * ub[i];
        }
        #pragma unroll
        for (int j = 0; j < 4; ++j) {
            float* op = out + ((size_t)r * NB + b0 + bt2 * 4 + j) * ND + c2 * 64 + Dt * 4;
            *(float4*)op = make_float4(o[j][0], o[j][1], o[j][2], o[j][3]);
        }
    }
}

extern "C" void kernel_launch(void* const* d_in, const int* in_sizes, int n_in,
                              void* d_out, int out_size, void* d_ws, size_t ws_size,
                              hipStream_t stream) {
    const float* x  = (const float*)d_in[0];
    const float* Us = (const float*)d_in[1];
    float* out = (float*)d_out;

    if (ws_size >= (size_t)WS_NEED) {
        prep_kernel<<<dim3(1104), 256, 0, stream>>>(x, Us, (char*)d_ws);
        ksub_mfma7<<<dim3(256), 256, 0, stream>>>((const char*)d_ws, out);
    } else {
        gram_kernel<<<dim3(NR * NK), 128, 0, stream>>>(Us, (float*)d_ws);
        ksub_fused<<<dim3(NB / 64, NR), 256, 0, stream>>>(x, Us, (float*)d_ws, out);
    }
}

// Round 11
// 104.814 us; speedup vs baseline: 1.0166x; 1.0166x over previous
//
#include <hip/hip_runtime.h>
#include <math.h>

typedef unsigned short ushort_t;
typedef unsigned int uint32_tt;
typedef __attribute__((ext_vector_type(8))) short bf16x8;
typedef __attribute__((ext_vector_type(4))) float f32x4;

#define NR   8
#define NK   10
#define ND   256
#define NDL  10
#define NB   4096
#define NN   100
#define NP   112      // phase-1 padded n (7*16)
#define NP2  128      // phase-3 padded K over n (4*32)

// ---- workspace layout (bytes) ----
#define WS_GP   0                          // fp32 Gp[8][1000]
#define WS_XB   32768                      // bf16 x[4096][256] = 2,097,152
#define WS_U1   (32768 + 2097152)          // bf16 U1[8][112][256] (n-major, D contig)
#define WS_U2   (WS_U1 + 458752)           // bf16 U2[8][256][128] (D-major, n contig)
#define WS_NEED (WS_U2 + 524288)           // 3,112,960

__device__ __forceinline__ ushort_t f2bf(float f) {
    uint32_tt u = __float_as_uint(f);
    u = (u + 0x7FFF + ((u >> 16) & 1)) >> 16;   // RNE
    return (ushort_t)u;
}

// =====================================================================
// Prep, grid 336 x 256:
//  bid < 80 : one block per (r,k): Us[rk] 10KB -> LDS, emit Gram (fp32)
//             + U1 slice + U2 slice, coalesced.
//  bid >= 80: 256 blocks, grid-stride x->bf16 (4 float4/thread).
// (was 1104 tiny blocks / ~11 us; traffic is only ~6 MB -> ~5 us)
// =====================================================================
__global__ __launch_bounds__(256) void prep_kernel(const float* __restrict__ x,
                                                   const float* __restrict__ Us,
                                                   char* __restrict__ ws) {
    __shared__ float lu[ND * NDL];     // 10 KB, layout [D][d] stride 10
    const int bid = blockIdx.x, tid = threadIdx.x;

    if (bid >= 80) {
        // ---- x -> bf16, 4 float4s per thread, coalesced ----
        ushort_t* xb = (ushort_t*)(ws + WS_XB);
        const int base = (bid - 80) * 1024;
        #pragma unroll
        for (int v = 0; v < 4; ++v) {
            int i = base + v * 256 + tid;
            float4 vv = ((const float4*)x)[i];
            uint32_tt p0 = (uint32_tt)f2bf(vv.x) | ((uint32_tt)f2bf(vv.y) << 16);
            uint32_tt p1 = (uint32_tt)f2bf(vv.z) | ((uint32_tt)f2bf(vv.w) << 16);
            ((uint2*)xb)[i] = make_uint2(p0, p1);
        }
        return;
    }

    const int rk = bid;                      // 0..79
    const int r  = rk / NK, k = rk - r * NK;
    const float* U = Us + (size_t)rk * ND * NDL;
    for (int i = tid; i < 640; i += 256)
        ((float4*)lu)[i] = ((const float4*)U)[i];
    __syncthreads();

    // ---- Gram: Gp = 10*I - 5*U^T U (fp32 -> logits stay accurate) ----
    float* Gp = (float*)(ws + WS_GP);
    if (tid < NDL * NDL) {
        int d1 = tid / NDL, d2 = tid - d1 * NDL;
        float acc = 0.f;
        #pragma unroll 8
        for (int Di = 0; Di < ND; ++Di)
            acc += lu[Di * NDL + d1] * lu[Di * NDL + d2];
        Gp[(size_t)rk * 100 + tid] = (d1 == d2 ? 10.0f : 0.0f) - 5.0f * acc;
    }

    // ---- U1[r][k*10+d][D] bf16, coalesced in D ----
    ushort_t* u1 = (ushort_t*)(ws + WS_U1);
    for (int p = tid; p < ND * NDL; p += 256) {
        int d = p >> 8, D = p & 255;
        u1[((size_t)r * NP + k * NDL + d) * ND + D] = f2bf(lu[D * NDL + d]);
    }

    // ---- U2[r][D][k*10..k*10+10) bf16, one D-row per thread ----
    ushort_t* u2 = (ushort_t*)(ws + WS_U2);
    {
        int D = tid;
        uint32_tt* dst = (uint32_tt*)(u2 + ((size_t)r * ND + D) * NP2 + k * NDL);
        const float* src = lu + D * NDL;
        #pragma unroll
        for (int j = 0; j < 5; ++j)
            dst[j] = (uint32_tt)f2bf(src[2 * j]) | ((uint32_tt)f2bf(src[2 * j + 1]) << 16);
    }

    // ---- zero pads (k==9 block only) ----
    if (k == NK - 1) {
        for (int p = tid; p < 12 * ND; p += 256) {
            int n = p >> 8, D = p & 255;
            u1[((size_t)r * NP + 100 + n) * ND + D] = 0;
        }
        uint32_tt* u2u = (uint32_tt*)u2;
        #pragma unroll
        for (int j = 0; j < 14; ++j)
            u2u[((size_t)r * ND + tid) * (NP2 / 2) + 50 + j] = 0;
    }
}

// =====================================================================
// Main MFMA kernel — R8's proven ksub_mfma6 (best total 106.0) with ONE
// change: epilogue stores are NONTEMPORAL. Theory: ksub is pinned at
// ~41 us across 3 designs because its window is HBM-traffic-bound, and
// FETCH=50MB includes ~32MB of write-allocate reads on the out stream.
// nt stores (full 64B lines: each wave writes 1KB contiguous) skip the
// allocate read.
// Grid 1024 x 256 (4 blocks/CU; LDS 37.3K x4 = 149K < 160K; lb(256,2)
// keeps natural VGPR alloc — lb(...,4) forced VGPR=64 in r4/r7).
// =====================================================================
__global__ __launch_bounds__(256, 2) void ksub_mfma8(const char* __restrict__ ws,
                                                     float* __restrict__ out) {
    __shared__ __align__(16) char smem[37280];
    float*    zbuf = (float*)smem;               // [32][100] fp32
    ushort_t* wTb  = (ushort_t*)smem;            // [32][136] bf16 (overlay)
    float*    ot   = (float*)smem;               // [32][260] fp32 (overlay, epilogue)
    float*    gp   = (float*)(smem + 33280);     // [1000] fp32

    const int tid  = threadIdx.x;
    const int w    = tid >> 6;
    const int lane = tid & 63;
    const int c    = lane & 15;
    const int q    = lane >> 4;
    const int bid  = blockIdx.x;
    const int xcd  = bid & 7;
    const int idx  = bid >> 3;                   // 0..127
    const int r    = idx & 7;
    const int b0   = (xcd * 16 + (idx >> 3)) * 32;
    const int bloc = (w & 1) * 16 + c;           // local b col 0..31
    const int pair = w >> 1;                     // wave pair 0/1

    const ushort_t* xb  = (const ushort_t*)(ws + WS_XB) + (size_t)(b0 + bloc) * ND + q * 8;
    const ushort_t* u1g = (const ushort_t*)(ws + WS_U1) + (size_t)r * NP * ND + c * ND + q * 8;
    const ushort_t* u2g = (const ushort_t*)(ws + WS_U2) + (size_t)r * ND * NP2 + c * NP2 + q * 8;
    const float*    gpg = (const float*)(ws + WS_GP) + (size_t)r * 1000;

    for (int i = tid; i < 1000; i += 256) gp[i] = gpg[i];

    // ---------------- phase 1: direct-global fragments ----------------
    bf16x8 xfr[8];
    #pragma unroll
    for (int Dc = 0; Dc < 8; ++Dc)
        xfr[Dc] = *(const bf16x8*)(xb + Dc * 32);

    f32x4 acc1[4];
    #pragma unroll
    for (int t = 0; t < 4; ++t) acc1[t] = (f32x4){0.f, 0.f, 0.f, 0.f};

    #pragma unroll
    for (int Dc = 0; Dc < 8; ++Dc) {
        bf16x8 a[4];
        #pragma unroll
        for (int tt = 0; tt < 4; ++tt) {
            int t = pair * 4 + tt;
            if (t < 7)                            // wave-uniform predicate
                a[tt] = *(const bf16x8*)(u1g + t * 16 * ND + Dc * 32);
        }
        #pragma unroll
        for (int tt = 0; tt < 4; ++tt) {
            int t = pair * 4 + tt;
            if (t < 7)
                acc1[tt] = __builtin_amdgcn_mfma_f32_16x16x32_bf16(a[tt], xfr[Dc], acc1[tt], 0, 0, 0);
        }
    }

    // ---- prefetch phase-3 first A-chunk (nc=0; softmax-independent) ----
    const int Dbase = pair * 128;
    bf16x8 a3[8];
    #pragma unroll
    for (int jj = 0; jj < 8; ++jj)
        a3[jj] = *(const bf16x8*)(u2g + (size_t)(Dbase + jj * 16) * NP2);

    // ---- dump Z^T C-frags: row n = t*16+q*4+reg, col b = bloc ----
    #pragma unroll
    for (int tt = 0; tt < 4; ++tt) {
        int t = pair * 4 + tt;
        if (t < 7) {
            #pragma unroll
            for (int rg = 0; rg < 4; ++rg) {
                int n = t * 16 + q * 4 + rg;
                if (n < NN) zbuf[bloc * 100 + n] = acc1[tt][rg];
            }
        }
    }
    __syncthreads();

    // ---------------- softmax: b = tid>>3, k split on 8 lanes ----------------
    const int bsm = tid >> 3;
    const int kq  = tid & 7;
    float zk[2][10], ee[2];
    {
        const float* zr = zbuf + bsm * 100;
        float L[2];
        #pragma unroll
        for (int jj = 0; jj < 2; ++jj) {
            int k = kq + 8 * jj;
            L[jj] = -1e30f;
            if (k < NK) {
                #pragma unroll
                for (int d = 0; d < 10; ++d) zk[jj][d] = zr[k * 10 + d];
                const float* g = gp + k * 100;
                float acc = 0.f;
                #pragma unroll
                for (int d1 = 0; d1 < 10; ++d1) {
                    float t2 = 0.f;
                    #pragma unroll
                    for (int d2 = 0; d2 < 10; ++d2) t2 += g[d1 * 10 + d2] * zk[jj][d2];
                    acc += t2 * zk[jj][d1];
                }
                L[jj] = acc;
            }
        }
        float m = fmaxf(L[0], L[1]);
        m = fmaxf(m, __shfl_xor(m, 1));
        m = fmaxf(m, __shfl_xor(m, 2));
        m = fmaxf(m, __shfl_xor(m, 4));
        float s = 0.f;
        #pragma unroll
        for (int jj = 0; jj < 2; ++jj) {
            ee[jj] = (kq + 8 * jj < NK) ? __expf(L[jj] - m) : 0.f;
            s += ee[jj];
        }
        s += __shfl_xor(s, 1);
        s += __shfl_xor(s, 2);
        s += __shfl_xor(s, 4);
        float inv = 1.0f / s;
        #pragma unroll
        for (int jj = 0; jj < 2; ++jj) ee[jj] *= inv;
    }
    __syncthreads();               // all zbuf reads done; wTb overlay safe

    #pragma unroll
    for (int jj = 0; jj < 2; ++jj) {
        int k = kq + 8 * jj;
        if (k < NK) {
            #pragma unroll
            for (int d = 0; d < 10; ++d)
                wTb[bsm * 136 + k * 10 + d] = f2bf(ee[jj] * zk[jj][d]);
        }
    }
    // zero-pad wTb n in [100,128): 14 uints per row, ALL 32 rows
    {
        int row = tid >> 4, p = tid & 15;
        if (row < 32 && p < 14) ((uint32_tt*)wTb)[row * 68 + 50 + p] = 0;
        row = (tid + 256) >> 4;
        if (row < 32 && p < 14) ((uint32_tt*)wTb)[row * 68 + 50 + p] = 0;
    }
    __syncthreads();

    // ---------------- phase 3: direct-global A, LDS B (D-half per pair) ----
    f32x4 acc3[8];
    #pragma unroll
    for (int t = 0; t < 8; ++t) acc3[t] = (f32x4){0.f, 0.f, 0.f, 0.f};

    #pragma unroll
    for (int nc = 0; nc < 4; ++nc) {
        bf16x8 bfr = *(const bf16x8*)(wTb + bloc * 136 + nc * 32 + q * 8);
        bf16x8 a[8];
        if (nc == 0) {
            #pragma unroll
            for (int jj = 0; jj < 8; ++jj) a[jj] = a3[jj];
        } else {
            #pragma unroll
            for (int jj = 0; jj < 8; ++jj)
                a[jj] = *(const bf16x8*)(u2g + (size_t)(Dbase + jj * 16) * NP2 + nc * 32);
        }
        #pragma unroll
        for (int jj = 0; jj < 8; ++jj)
            acc3[jj] = __builtin_amdgcn_mfma_f32_16x16x32_bf16(a[jj], bfr, acc3[jj], 0, 0, 0);
    }

    // ---- epilogue: LDS transpose -> per-wave 1KB NONTEMPORAL stores ----
    __syncthreads();               // wTb reads complete before ot overlay
    #pragma unroll
    for (int jj = 0; jj < 8; ++jj)
        *(f32x4*)(ot + bloc * 260 + Dbase + jj * 16 + q * 4) = acc3[jj];
    __syncthreads();
    const size_t orow = (size_t)r * NB + b0;
    #pragma unroll
    for (int i = 0; i < 8; ++i) {
        int g4 = i * 256 + tid;        // float4 index over 32 rows x 64
        int b  = g4 >> 6;
        int c4 = g4 & 63;
        f32x4 v = *(const f32x4*)(ot + b * 260 + c4 * 4);
        __builtin_nontemporal_store(v, (f32x4*)(out + (orow + b) * ND + c4 * 4));
    }
}

// =====================================================================
// Fallback (round-2 verified path) if ws is too small for bf16 buffers
// =====================================================================
#define XS_S 68
#define US_S 132
#define ZB_S 104
#define WT_S 68
#define U2_S 68
#define OFF_WT 0
#define OFF_SH 6800
#define OFF_GP 13600
#define SMEM_F 14600

__global__ __launch_bounds__(128) void gram_kernel(const float* __restrict__ Us,
                                                   float* __restrict__ Gp) {
    int rk = blockIdx.x;
    const float* U = Us + (size_t)rk * ND * NDL;
    __shared__ float u[ND * NDL];
    for (int i = threadIdx.x; i < ND * NDL; i += blockDim.x) u[i] = U[i];
    __syncthreads();
    int e = threadIdx.x;
    if (e < NDL * NDL) {
        int d1 = e / NDL, d2 = e % NDL;
        float acc = 0.f;
        #pragma unroll 8
        for (int Di = 0; Di < ND; ++Di)
            acc += u[Di * NDL + d1] * u[Di * NDL + d2];
        Gp[(size_t)rk * (NDL * NDL) + e] = (d1 == d2 ? 10.0f : 0.0f) - 5.0f * acc;
    }
}

__global__ __launch_bounds__(256, 2) void ksub_fused(const float* __restrict__ x,
                                                     const float* __restrict__ Us,
                                                     const float* __restrict__ Gp,
                                                     float* __restrict__ out) {
    __shared__ float smemf[SMEM_F];
    float* wT   = smemf + OFF_WT;
    float* xsf  = smemf + OFF_SH;
    float* usf  = smemf + OFF_SH + 2176;
    float* zbuf = smemf + OFF_SH;
    float* u2   = smemf + OFF_SH;
    float* gp   = smemf + OFF_GP;

    const int tid = threadIdx.x;
    const int r   = blockIdx.y;
    const int b0  = blockIdx.x * 64;

    for (int i = tid; i < NK * NDL * NDL; i += 256)
        gp[i] = Gp[(size_t)r * (NK * NDL * NDL) + i];

    const int nt = tid & 15;
    const int bt = tid >> 4;
    float acc[4][8];
    #pragma unroll
    for (int j = 0; j < 4; ++j)
        #pragma unroll
        for (int i = 0; i < 8; ++i) acc[j][i] = 0.f;

    for (int cch = 0; cch < 8; ++cch) {
        __syncthreads();
        for (int i = tid; i < 512; i += 256) {
            int b = i >> 3, f = i & 7;
            float4 v = ((const float4*)(x + (size_t)(b0 + b) * ND))[cch * 8 + f];
            float* dst = xsf + (f * 4) * XS_S + b;
            dst[0] = v.x; dst[XS_S] = v.y; dst[2 * XS_S] = v.z; dst[3 * XS_S] = v.w;
        }
        for (int p = tid; p < 320; p += 256) {
            int k = p >> 5, Dl = p & 31;
            const float* g = Us + ((size_t)((r * NK + k) * ND) + cch * 32 + Dl) * NDL;
            float* dst = usf + Dl * US_S + k * NDL;
            #pragma unroll
            for (int d = 0; d < 10; ++d) dst[d] = g[d];
        }
        __syncthreads();
        #pragma unroll 4
        for (int Dl = 0; Dl < 32; ++Dl) {
            float4 xv = *(const float4*)(xsf + Dl * XS_S + bt * 4);
            float4 ua = *(const float4*)(usf + Dl * US_S + nt * 8);
            float4 ub = *(const float4*)(usf + Dl * US_S + nt * 8 + 4);
            float xa[4] = {xv.x, xv.y, xv.z, xv.w};
            float uu[8] = {ua.x, ua.y, ua.z, ua.w, ub.x, ub.y, ub.z, ub.w};
            #pragma unroll
            for (int j = 0; j < 4; ++j)
                #pragma unroll
                for (int i = 0; i < 8; ++i) acc[j][i] += xa[j] * uu[i];
        }
    }
    __syncthreads();
    if (nt < 12) {
        #pragma unroll
        for (int j = 0; j < 4; ++j) {
            float* zp = zbuf + (bt * 4 + j) * ZB_S + nt * 8;
            *(float4*)(zp)     = make_float4(acc[j][0], acc[j][1], acc[j][2], acc[j][3]);
            *(float4*)(zp + 4) = make_float4(acc[j][4], acc[j][5], acc[j][6], acc[j][7]);
        }
    } else if (nt == 12) {
        #pragma unroll
        for (int j = 0; j < 4; ++j) {
            float* zp = zbuf + (bt * 4 + j) * ZB_S + 96;
            *(float4*)(zp) = make_float4(acc[j][0], acc[j][1], acc[j][2], acc[j][3]);
        }
    }
    __syncthreads();
    if (tid < 64) {
        const int b_l = tid;
        const float* zrow = zbuf + b_l * ZB_S;
        float L[10];
        #pragma unroll
        for (int k = 0; k < NK; ++k) {
            float zkk[10];
            #pragma unroll
            for (int d = 0; d < 10; ++d) zkk[d] = zrow[k * 10 + d];
            const float* g = gp + k * 100;
            float a2 = 0.f;
            #pragma unroll
            for (int d1 = 0; d1 < 10; ++d1) {
                float t = 0.f;
                #pragma unroll
                for (int d2 = 0; d2 < 10; ++d2) t += g[d1 * 10 + d2] * zkk[d2];
                a2 += t * zkk[d1];
            }
            L[k] = a2;
        }
        float m = L[0];
        #pragma unroll
        for (int k = 1; k < NK; ++k) m = fmaxf(m, L[k]);
        float e[10], s = 0.f;
        #pragma unroll
        for (int k = 0; k < NK; ++k) { e[k] = __expf(L[k] - m); s += e[k]; }
        float inv = 1.0f / s;
        #pragma unroll
        for (int k = 0; k < NK; ++k) {
            float ck = e[k] * inv;
            #pragma unroll
            for (int d = 0; d < 10; ++d)
                wT[(k * 10 + d) * WT_S + b_l] = ck * zrow[k * 10 + d];
        }
    }
    const int Dt  = tid & 15;
    const int bt2 = tid >> 4;
    for (int c2 = 0; c2 < 4; ++c2) {
        __syncthreads();
        for (int p = tid; p < 640; p += 256) {
            int k = p >> 6, Dl = p & 63;
            const float* g = Us + ((size_t)((r * NK + k) * ND) + c2 * 64 + Dl) * NDL;
            float* dst = u2 + (k * NDL) * U2_S + Dl;
            #pragma unroll
            for (int d = 0; d < 10; ++d) dst[d * U2_S] = g[d];
        }
        __syncthreads();
        float o[4][4];
        #pragma unroll
        for (int j = 0; j < 4; ++j)
            #pragma unroll
            for (int i = 0; i < 4; ++i) o[j][i] = 0.f;
        #pragma unroll 4
        for (int n = 0; n < NN; ++n) {
            float4 wv = *(const float4*)(wT + n * WT_S + bt2 * 4);
            float4 uv = *(const float4*)(u2 + n * U2_S + Dt * 4);
            float wa[4] = {wv.x, wv.y, wv.z, wv.w};
            float ub[4] = {uv.x, uv.y, uv.z, uv.w};
            #pragma unroll
            for (int j = 0; j < 4; ++j)
                #pragma unroll
                for (int i = 0; i < 4; ++i) o[j][i] += wa[j] * ub[i];
        }
        #pragma unroll
        for (int j = 0; j < 4; ++j) {
            float* op = out + ((size_t)r * NB + b0 + bt2 * 4 + j) * ND + c2 * 64 + Dt * 4;
            *(float4*)op = make_float4(o[j][0], o[j][1], o[j][2], o[j][3]);
        }
    }
}

extern "C" void kernel_launch(void* const* d_in, const int* in_sizes, int n_in,
                              void* d_out, int out_size, void* d_ws, size_t ws_size,
                              hipStream_t stream) {
    const float* x  = (const float*)d_in[0];
    const float* Us = (const float*)d_in[1];
    float* out = (float*)d_out;

    if (ws_size >= (size_t)WS_NEED) {
        prep_kernel<<<dim3(336), 256, 0, stream>>>(x, Us, (char*)d_ws);
        ksub_mfma8<<<dim3(1024), 256, 0, stream>>>((const char*)d_ws, out);
    } else {
        gram_kernel<<<dim3(NR * NK), 128, 0, stream>>>(Us, (float*)d_ws);
        ksub_fused<<<dim3(NB / 64, NR), 256, 0, stream>>>(x, Us, (float*)d_ws, out);
    }
}